// Round 13
// baseline (86.026 us; speedup 1.0000x reference)
//
#include <hip/hip_runtime.h>
#include <hip/hip_bf16.h>

#define NB 256      // batch == queries == classes
#define NL 256      // clips
#define SCALE 100.0f  // 1/TAU

typedef __attribute__((ext_vector_type(4))) unsigned int u32x4;
typedef __attribute__((ext_vector_type(8))) __bf16 bfrag8;
typedef __attribute__((ext_vector_type(4))) float f32x4;

static __device__ __forceinline__ unsigned int pack2bf(float a, float b) {
  union { float f; unsigned int u; } ua, ub;
  ua.f = a; ub.f = b;
  unsigned int ra = (ua.u + 0x7FFFu + ((ua.u >> 16) & 1u)) >> 16;
  unsigned int rb = (ub.u + 0x7FFFu + ((ub.u >> 16) & 1u)) & 0xFFFF0000u;
  return ra | rb;
}

// ---------------------------------------------------------------------------
// Kernel 1 (round-13: VECTORIZED READS, clean).  The invariant across every
// ~57us exp_t variant was scalar 4B/lane reads (256B/instr) — the known
// 2-2.5x penalty (2.3 vs 6.3 TB/s matches).  Now: lane = f32x4 across i
// (every read instr = 1KB contiguous), 8 l per thread per i -> full-16B
// ds_write_b128 staging, 16B-granular XOR swizzle (8 chunks x 8 lanes =
// bank-throughput-optimal, no b64 half-slot conflicts like R11).
// 512-thread blocks, grid (NB, 2, 2 l-halves), 40KB LDS -> 4 blocks/CU,
// __launch_bounds__(512,8) caps VGPR at 64.  Sums: per-thread partials ->
// LDS combine -> atomicAdd (2-way, sums pre-zeroed).
//   dst[b][i][l] = bf16(exp(src[b,l,i]))   (UNMASKED; mask lives in gemm)
//   sums[b][i]  += sum_{l in half} exp(src[b,l,i])
// ---------------------------------------------------------------------------
__global__ __launch_bounds__(512, 8) void exp_t(
    const float* __restrict__ x, const float* __restrict__ tgt,
    unsigned int* __restrict__ xsT, unsigned int* __restrict__ tsT,
    float* __restrict__ sumx, float* __restrict__ sumt)
{
  const int b  = blockIdx.x;
  const bool is_t = (blockIdx.y != 0);
  const int z  = blockIdx.z;        // 128-l half
  const int tid = threadIdx.x;
  const int i4 = tid & 63;          // f32x4 index across i (i = 4*i4..4*i4+3)
  const int lg = tid >> 6;          // l-octet group (0..7)
  const f32x4* src4 = reinterpret_cast<const f32x4*>(
      (is_t ? tgt : x) + (size_t)b * (NL * NB));
  unsigned int* dstb = (is_t ? tsT : xsT);  // u32 units, layout [b][i][l/2]

  __shared__ __align__(16) unsigned char stg[256 * 128];  // [256 i][64 l] bf16, swizzled
  __shared__ float s_ps[8][256];

  float psum[4] = {0.f, 0.f, 0.f, 0.f};

  #pragma unroll
  for (int r = 0; r < 2; ++r) {
    const int lbase = z * 128 + r * 64;
    // 8 loads, each wave-instr = 64 lanes x 16B = 1KB contiguous
    f32x4 rv[8];
    #pragma unroll
    for (int k = 0; k < 8; ++k)
      rv[k] = src4[(size_t)(lbase + lg * 8 + k) * 64 + i4];
    // per owned i-row: exp, accumulate, pack 8 l -> 16B, one b128 store
    #pragma unroll
    for (int ii = 0; ii < 4; ++ii) {
      float e[8];
      #pragma unroll
      for (int k = 0; k < 8; ++k) {
        e[k] = __expf(rv[k][ii]);
        psum[ii] += e[k];
      }
      u32x4 pk;
      pk.x = pack2bf(e[0], e[1]);
      pk.y = pack2bf(e[2], e[3]);
      pk.z = pack2bf(e[4], e[5]);
      pk.w = pack2bf(e[6], e[7]);
      const int row = i4 * 4 + ii;
      const int ch  = lg ^ (i4 & 7);   // == lg ^ ((row>>2)&7); 8 chunks x 8 lanes
      *reinterpret_cast<u32x4*>(&stg[row * 128 + (ch << 4)]) = pk;
    }
    __syncthreads();
    // readout: 64 rows x 128B per pass, 8 lanes per row -> full lines
    const int c = tid & 7;
    #pragma unroll
    for (int k = 0; k < 4; ++k) {
      const int row = (tid >> 3) + 64 * k;
      const int cp  = c ^ ((row >> 2) & 7);
      u32x4 q = *reinterpret_cast<const u32x4*>(&stg[row * 128 + (cp << 4)]);
      *reinterpret_cast<u32x4*>(
          dstb + ((size_t)b * 256 + row) * 128 + z * 64 + r * 32 + c * 4) = q;
    }
    if (r == 0) __syncthreads();   // before overwriting stg
  }

  // sums: per-thread partials -> LDS -> one atomic per (b,i) per half
  #pragma unroll
  for (int ii = 0; ii < 4; ++ii) s_ps[lg][i4 * 4 + ii] = psum[ii];
  __syncthreads();
  if (tid < 256) {
    float tot = 0.f;
    #pragma unroll
    for (int k = 0; k < 8; ++k) tot += s_ps[k][tid];
    atomicAdd((is_t ? sumt : sumx) + (size_t)b * 256 + tid, tot);
  }
}

// ---------------------------------------------------------------------------
// Kernel 2 (VERBATIM R12 — lean gemm + mask on the B-staging path).
//   raw[j,c]   = sum_l ex[j,l] * (et[c,l] & m[l])
//   logits     = SCALE * raw * irx[j] * ict[c]      (rcp's staged in LDS)
// then log-softmax over c + label-weighted diag pick -> atomicAdd.
// XCD remap, [b][i][l] ws reads, rule #20 static acc indexing.
// ---------------------------------------------------------------------------
__global__ __launch_bounds__(256, 2) void gemm_lse(
    const unsigned short* __restrict__ xsT,
    const unsigned short* __restrict__ tsT,
    const float* __restrict__ sumx,
    const float* __restrict__ sumt,
    const int* __restrict__ mask,
    const int* __restrict__ label_mat,
    float* __restrict__ out)
{
  const int n  = blockIdx.x;
  const int g  = n & 7;
  const int q  = n >> 3;
  const int i  = ((q >> 2) << 3) + g;
  const int jt = q & 3;
  const int t  = threadIdx.x;
  const int w  = t >> 6;
  const int lane = t & 63;

  __shared__ __align__(16) unsigned char As[64 * 128];    // [64 j][64 l] bf16, swizzled
  __shared__ __align__(16) unsigned char Bs[256 * 128];   // [256 c][64 l] bf16, swizzled
  __shared__ __align__(16) unsigned short s_mask[NL];     // 0xFFFF / 0 per l
  __shared__ float s_irx[64];    // SCALE * rcp(sumx[j][i])
  __shared__ float s_ict[256];   //         rcp(sumt[c][i])
  __shared__ float s_rmax[4][64];
  __shared__ float s_rsum[4][64];
  __shared__ float s_diag[64];

  const int srow = t >> 3;
  const int sch  = t & 7;

  f32x4 acc[4][4];
  #pragma unroll
  for (int a = 0; a < 4; ++a)
    #pragma unroll
    for (int cc = 0; cc < 4; ++cc) acc[a][cc] = f32x4{0.f, 0.f, 0.f, 0.f};

  u32x4 areg[2], breg[8];

  auto load_chunk = [&](int kc) {
    const int kofs = kc * 64;
    #pragma unroll
    for (int r = 0; r < 2; ++r) {
      int row = srow + r * 32;
      areg[r] = *reinterpret_cast<const u32x4*>(
          xsT + ((size_t)(jt * 64 + row) * 256 + i) * 256 + kofs + sch * 8);
    }
    #pragma unroll
    for (int r = 0; r < 8; ++r) {
      int row = srow + r * 32;
      breg[r] = *reinterpret_cast<const u32x4*>(
          tsT + ((size_t)row * 256 + i) * 256 + kofs + sch * 8);
    }
  };
  auto store_chunk = [&](int kc) {
    u32x4 mk = *reinterpret_cast<const u32x4*>(&s_mask[kc * 64 + sch * 8]);
    #pragma unroll
    for (int r = 0; r < 2; ++r) {
      int row = srow + r * 32;
      *reinterpret_cast<u32x4*>(&As[row * 128 + ((sch ^ (row & 7)) << 4)]) = areg[r];
    }
    #pragma unroll
    for (int r = 0; r < 8; ++r) {
      int row = srow + r * 32;
      u32x4 bm = breg[r];
      bm.x &= mk.x; bm.y &= mk.y; bm.z &= mk.z; bm.w &= mk.w;
      *reinterpret_cast<u32x4*>(&Bs[row * 128 + ((sch ^ (row & 7)) << 4)]) = bm;
    }
  };

  load_chunk(0);
  s_mask[t] = (mask[i * NL + t] > 0) ? (unsigned short)0xFFFFu : (unsigned short)0u;
  s_ict[t] = __builtin_amdgcn_rcpf(sumt[(size_t)t * 256 + i]);
  if (t < 64)
    s_irx[t] = SCALE * __builtin_amdgcn_rcpf(sumx[(size_t)(jt * 64 + t) * 256 + i]);
  __syncthreads();

  #pragma unroll
  for (int kc = 0; kc < 4; ++kc) {
    store_chunk(kc);
    __syncthreads();
    if (kc < 3) load_chunk(kc + 1);
    #pragma unroll
    for (int kk = 0; kk < 2; ++kk) {
      const int co = kk * 4 + (lane >> 4);
      bfrag8 af[4], bfr[4];
      #pragma unroll
      for (int jf = 0; jf < 4; ++jf) {
        int row = jf * 16 + (lane & 15);
        af[jf] = *reinterpret_cast<const bfrag8*>(
            &As[row * 128 + ((co ^ (row & 7)) << 4)]);
      }
      #pragma unroll
      for (int cf = 0; cf < 4; ++cf) {
        int row = w * 64 + cf * 16 + (lane & 15);
        bfr[cf] = *reinterpret_cast<const bfrag8*>(
            &Bs[row * 128 + ((co ^ (row & 7)) << 4)]);
      }
      #pragma unroll
      for (int jf = 0; jf < 4; ++jf)
        #pragma unroll
        for (int cf = 0; cf < 4; ++cf)
          acc[jf][cf] = __builtin_amdgcn_mfma_f32_16x16x32_bf16(
              af[jf], bfr[cf], acc[jf][cf], 0, 0, 0);
    }
    __syncthreads();
  }

  // ---- epilogue: logits = s_irx[row] * s_ict[col] * raw ----
  const int rg = (lane >> 4) << 2;

  float fr[4][4], fc[4];
  #pragma unroll
  for (int jf = 0; jf < 4; ++jf)
    #pragma unroll
    for (int reg = 0; reg < 4; ++reg)
      fr[jf][reg] = s_irx[jf * 16 + rg + reg];
  #pragma unroll
  for (int cf = 0; cf < 4; ++cf)
    fc[cf] = s_ict[w * 64 + cf * 16 + (lane & 15)];
  #pragma unroll
  for (int jf = 0; jf < 4; ++jf)
    #pragma unroll
    for (int cf = 0; cf < 4; ++cf)
      #pragma unroll
      for (int reg = 0; reg < 4; ++reg)
        acc[jf][cf][reg] *= fr[jf][reg] * fc[cf];

  #pragma unroll
  for (int jf = 0; jf < 4; ++jf) {
    #pragma unroll
    for (int reg = 0; reg < 4; ++reg) {
      float m = fmaxf(fmaxf(acc[jf][0][reg], acc[jf][1][reg]),
                      fmaxf(acc[jf][2][reg], acc[jf][3][reg]));
      #pragma unroll
      for (int off = 1; off < 16; off <<= 1) m = fmaxf(m, __shfl_xor(m, off, 64));
      if ((lane & 15) == 0) s_rmax[w][jf * 16 + rg + reg] = m;
    }
  }
  if (w == (i >> 6) && (lane & 15) == (i & 15)) {
    const int cfd = (i >> 4) & 3;
    #pragma unroll
    for (int jf = 0; jf < 4; ++jf) {
      #pragma unroll
      for (int reg = 0; reg < 4; ++reg) {
        float v = acc[jf][0][reg];
        #pragma unroll
        for (int cf = 1; cf < 4; ++cf)
          v = (cfd == cf) ? acc[jf][cf][reg] : v;
        s_diag[jf * 16 + rg + reg] = v;
      }
    }
  }
  __syncthreads();

  #pragma unroll
  for (int jf = 0; jf < 4; ++jf) {
    #pragma unroll
    for (int reg = 0; reg < 4; ++reg) {
      int row = jf * 16 + rg + reg;
      float gm = fmaxf(fmaxf(s_rmax[0][row], s_rmax[1][row]),
                       fmaxf(s_rmax[2][row], s_rmax[3][row]));
      float sE = 0.f;
      #pragma unroll
      for (int cf = 0; cf < 4; ++cf) sE += __expf(acc[jf][cf][reg] - gm);
      #pragma unroll
      for (int off = 1; off < 16; off <<= 1) sE += __shfl_xor(sE, off, 64);
      if ((lane & 15) == 0) s_rsum[w][row] = sE;
    }
  }
  __syncthreads();

  float contrib = 0.f;
  if (t < 64) {
    const int row = t;
    float gm = fmaxf(fmaxf(s_rmax[0][row], s_rmax[1][row]),
                     fmaxf(s_rmax[2][row], s_rmax[3][row]));
    float tot = s_rsum[0][row] + s_rsum[1][row] + s_rsum[2][row] + s_rsum[3][row];
    float lse = __logf(tot) + gm;
    float lbl = (float)label_mat[i * NB + jt * 64 + row];
    contrib = lbl * (s_diag[row] - lse);
  }
  #pragma unroll
  for (int off = 32; off >= 1; off >>= 1) contrib += __shfl_down(contrib, off, 64);
  if (t == 0) atomicAdd(out, contrib * (-1.0f / 256.0f));
}

extern "C" void kernel_launch(void* const* d_in, const int* in_sizes, int n_in,
                              void* d_out, int out_size, void* d_ws, size_t ws_size,
                              hipStream_t stream) {
  const float* x   = (const float*)d_in[0];
  const float* tgt = (const float*)d_in[1];
  const int* mask  = (const int*)d_in[2];
  // d_in[3] = query_labels (unused by the reference computation)
  const int* label_mat = (const int*)d_in[4];
  float* out = (float*)d_out;

  unsigned int* xsT = (unsigned int*)d_ws;                       // 32 MiB bf16 [b][i][l]
  unsigned int* tsT = xsT + (size_t)NB * NB * NL / 2;            // 32 MiB bf16 [b][i][l]
  float* sumx = (float*)(tsT + (size_t)NB * NB * NL / 2);        // 256 KiB f32 [b][i]
  float* sumt = sumx + (size_t)NB * NB;                          // 256 KiB f32 [b][i]

  hipMemsetAsync(out, 0, sizeof(float), stream);
  hipMemsetAsync(sumx, 0, 2 * (size_t)NB * NB * sizeof(float), stream);
  exp_t<<<dim3(NB, 2, 2), 512, 0, stream>>>(x, tgt, xsT, tsT, sumx, sumt);
  gemm_lse<<<dim3(1024), 256, 0, stream>>>((const unsigned short*)xsT,
                                           (const unsigned short*)tsT,
                                           sumx, sumt, mask, label_mat, out);
}

// Round 14
// 75.883 us; speedup vs baseline: 1.1337x; 1.1337x over previous
//
#include <hip/hip_runtime.h>
#include <hip/hip_bf16.h>

#define NB 256      // batch == queries == classes
#define NL 256      // clips
#define SCALE 100.0f  // 1/TAU

typedef __attribute__((ext_vector_type(4))) unsigned int u32x4;
typedef __attribute__((ext_vector_type(8))) __bf16 bfrag8;
typedef __attribute__((ext_vector_type(4))) float f32x4;

static __device__ __forceinline__ unsigned int pack2bf(float a, float b) {
  union { float f; unsigned int u; } ua, ub;
  ua.f = a; ub.f = b;
  unsigned int ra = (ua.u + 0x7FFFu + ((ua.u >> 16) & 1u)) >> 16;
  unsigned int rb = (ub.u + 0x7FFFu + ((ub.u >> 16) & 1u)) & 0xFFFF0000u;
  return ra | rb;
}

// ---------------------------------------------------------------------------
// Kernel 1 (round-14 recombination).  exp_t is layout-invariant (R5 [i][b][l]
// 57us == R12 [b][i][l] 58us) but the GEMM is NOT (linear reads ~22us vs
// 128KB-strided 58us).  So: R12 structure verbatim, output back to [i][b][l]
// so the GEMM gets contiguous panels.  No mask here (costs +7us, R9).
//   dst[i][b][l] = bf16(exp(src[b,l,i]))
//   sums[b][i]   = sum_l exp(src[b,l,i])   (f32, direct store, free)
// ---------------------------------------------------------------------------
__global__ __launch_bounds__(1024, 2) void exp_t(
    const float* __restrict__ x, const float* __restrict__ tgt,
    unsigned int* __restrict__ xsT, unsigned int* __restrict__ tsT,
    float* __restrict__ sumx, float* __restrict__ sumt)
{
  const int b = blockIdx.x;
  const bool is_t = (blockIdx.y != 0);
  const int tid = threadIdx.x;
  const int i = tid & 255;
  const int h = tid >> 8;
  const float* src = (is_t ? tgt : x) + (size_t)b * (NL * NB) + i;
  unsigned int* dstb = (is_t ? tsT : xsT);  // u32 units, layout [i][b][l/2]

  __shared__ __align__(16) unsigned char stg[256 * 128];  // [i][64 l] bf16, swizzled
  __shared__ float s_sum[4][256];

  const int r0 = tid >> 3;  // writer rows r0 and r0+128
  const int c  = tid & 7;   // writer 16B chunk within 128B row-segment

  float tsum = 0.f;

  for (int lc = 0; lc < 4; ++lc) {
    float v[16];
    #pragma unroll
    for (int k = 0; k < 16; ++k)
      v[k] = __expf(src[(size_t)(lc * 64 + h * 16 + k) * NB]);
    #pragma unroll
    for (int k = 0; k < 16; ++k) tsum += v[k];
    u32x4 p0, p1;
    p0.x = pack2bf(v[0], v[1]);   p0.y = pack2bf(v[2], v[3]);
    p0.z = pack2bf(v[4], v[5]);   p0.w = pack2bf(v[6], v[7]);
    p1.x = pack2bf(v[8], v[9]);   p1.y = pack2bf(v[10], v[11]);
    p1.z = pack2bf(v[12], v[13]); p1.w = pack2bf(v[14], v[15]);
    *reinterpret_cast<u32x4*>(&stg[i * 128 + (((h * 2 + 0) ^ (i & 7)) << 4)]) = p0;
    *reinterpret_cast<u32x4*>(&stg[i * 128 + (((h * 2 + 1) ^ (i & 7)) << 4)]) = p1;
    __syncthreads();
    u32x4 q0 = *reinterpret_cast<const u32x4*>(&stg[r0 * 128 + ((c ^ (r0 & 7)) << 4)]);
    u32x4 q1 = *reinterpret_cast<const u32x4*>(&stg[(r0 + 128) * 128 + ((c ^ ((r0 + 128) & 7)) << 4)]);
    *reinterpret_cast<u32x4*>(dstb + ((size_t)r0 * 256 + b) * 128 + lc * 32 + c * 4) = q0;
    *reinterpret_cast<u32x4*>(dstb + ((size_t)(r0 + 128) * 256 + b) * 128 + lc * 32 + c * 4) = q1;
    __syncthreads();
  }

  s_sum[h][i] = tsum;
  __syncthreads();
  if (h == 0) {
    float* so = is_t ? sumt : sumx;
    so[(size_t)b * 256 + i] = s_sum[0][i] + s_sum[1][i] + s_sum[2][i] + s_sum[3][i];
  }
}

// ---------------------------------------------------------------------------
// Kernel 2 (lean R12 gemm + R3's LINEAR read addressing — the recombination).
// ws layout [i][b][l]: A panel (i, jt) = contiguous 32KB; B panel (i) =
// contiguous 128KB, shared by 4 XCD-pinned jt-blocks via L2.
//   raw[j,c]   = sum_l ex[j,l] * (et[c,l] & m[l])   (mask on B-staging)
//   logits     = SCALE * raw * irx[j] * ict[c]      (rcp's staged in LDS)
// then log-softmax over c + label-weighted diag pick -> atomicAdd.
// rule #20: all acc indexing compile-time.
// ---------------------------------------------------------------------------
__global__ __launch_bounds__(256, 2) void gemm_lse(
    const unsigned short* __restrict__ xsT,
    const unsigned short* __restrict__ tsT,
    const float* __restrict__ sumx,
    const float* __restrict__ sumt,
    const int* __restrict__ mask,
    const int* __restrict__ label_mat,
    float* __restrict__ out)
{
  const int n  = blockIdx.x;
  const int g  = n & 7;
  const int q  = n >> 3;
  const int i  = ((q >> 2) << 3) + g;
  const int jt = q & 3;
  const int t  = threadIdx.x;
  const int w  = t >> 6;
  const int lane = t & 63;

  __shared__ __align__(16) unsigned char As[64 * 128];    // [64 j][64 l] bf16, swizzled
  __shared__ __align__(16) unsigned char Bs[256 * 128];   // [256 c][64 l] bf16, swizzled
  __shared__ __align__(16) unsigned short s_mask[NL];     // 0xFFFF / 0 per l
  __shared__ float s_irx[64];    // SCALE * rcp(sumx[j][i])
  __shared__ float s_ict[256];   //         rcp(sumt[c][i])
  __shared__ float s_rmax[4][64];
  __shared__ float s_rsum[4][64];
  __shared__ float s_diag[64];

  const unsigned short* Ag = xsT + ((size_t)i * NB + jt * 64) * NL;  // contiguous 32KB
  const unsigned short* Bg = tsT + (size_t)i * NB * NL;              // contiguous 128KB

  const int srow = t >> 3;
  const int sch  = t & 7;

  f32x4 acc[4][4];
  #pragma unroll
  for (int a = 0; a < 4; ++a)
    #pragma unroll
    for (int cc = 0; cc < 4; ++cc) acc[a][cc] = f32x4{0.f, 0.f, 0.f, 0.f};

  u32x4 areg[2], breg[8];

  auto load_chunk = [&](int kc) {
    const int kofs = kc * 64;
    #pragma unroll
    for (int r = 0; r < 2; ++r) {
      int row = srow + r * 32;
      areg[r] = *reinterpret_cast<const u32x4*>(Ag + (size_t)row * NL + kofs + sch * 8);
    }
    #pragma unroll
    for (int r = 0; r < 8; ++r) {
      int row = srow + r * 32;
      breg[r] = *reinterpret_cast<const u32x4*>(Bg + (size_t)row * NL + kofs + sch * 8);
    }
  };
  auto store_chunk = [&](int kc) {
    u32x4 mk = *reinterpret_cast<const u32x4*>(&s_mask[kc * 64 + sch * 8]);
    #pragma unroll
    for (int r = 0; r < 2; ++r) {
      int row = srow + r * 32;
      *reinterpret_cast<u32x4*>(&As[row * 128 + ((sch ^ (row & 7)) << 4)]) = areg[r];
    }
    #pragma unroll
    for (int r = 0; r < 8; ++r) {
      int row = srow + r * 32;
      u32x4 bm = breg[r];
      bm.x &= mk.x; bm.y &= mk.y; bm.z &= mk.z; bm.w &= mk.w;
      *reinterpret_cast<u32x4*>(&Bs[row * 128 + ((sch ^ (row & 7)) << 4)]) = bm;
    }
  };

  load_chunk(0);
  s_mask[t] = (mask[i * NL + t] > 0) ? (unsigned short)0xFFFFu : (unsigned short)0u;
  s_ict[t] = __builtin_amdgcn_rcpf(sumt[(size_t)t * 256 + i]);
  if (t < 64)
    s_irx[t] = SCALE * __builtin_amdgcn_rcpf(sumx[(size_t)(jt * 64 + t) * 256 + i]);
  __syncthreads();

  #pragma unroll
  for (int kc = 0; kc < 4; ++kc) {
    store_chunk(kc);
    __syncthreads();
    if (kc < 3) load_chunk(kc + 1);
    #pragma unroll
    for (int kk = 0; kk < 2; ++kk) {
      const int co = kk * 4 + (lane >> 4);
      bfrag8 af[4], bfr[4];
      #pragma unroll
      for (int jf = 0; jf < 4; ++jf) {
        int row = jf * 16 + (lane & 15);
        af[jf] = *reinterpret_cast<const bfrag8*>(
            &As[row * 128 + ((co ^ (row & 7)) << 4)]);
      }
      #pragma unroll
      for (int cf = 0; cf < 4; ++cf) {
        int row = w * 64 + cf * 16 + (lane & 15);
        bfr[cf] = *reinterpret_cast<const bfrag8*>(
            &Bs[row * 128 + ((co ^ (row & 7)) << 4)]);
      }
      #pragma unroll
      for (int jf = 0; jf < 4; ++jf)
        #pragma unroll
        for (int cf = 0; cf < 4; ++cf)
          acc[jf][cf] = __builtin_amdgcn_mfma_f32_16x16x32_bf16(
              af[jf], bfr[cf], acc[jf][cf], 0, 0, 0);
    }
    __syncthreads();
  }

  // ---- epilogue: logits = s_irx[row] * s_ict[col] * raw ----
  const int rg = (lane >> 4) << 2;

  float fr[4][4], fc[4];
  #pragma unroll
  for (int jf = 0; jf < 4; ++jf)
    #pragma unroll
    for (int reg = 0; reg < 4; ++reg)
      fr[jf][reg] = s_irx[jf * 16 + rg + reg];
  #pragma unroll
  for (int cf = 0; cf < 4; ++cf)
    fc[cf] = s_ict[w * 64 + cf * 16 + (lane & 15)];
  #pragma unroll
  for (int jf = 0; jf < 4; ++jf)
    #pragma unroll
    for (int cf = 0; cf < 4; ++cf)
      #pragma unroll
      for (int reg = 0; reg < 4; ++reg)
        acc[jf][cf][reg] *= fr[jf][reg] * fc[cf];

  #pragma unroll
  for (int jf = 0; jf < 4; ++jf) {
    #pragma unroll
    for (int reg = 0; reg < 4; ++reg) {
      float m = fmaxf(fmaxf(acc[jf][0][reg], acc[jf][1][reg]),
                      fmaxf(acc[jf][2][reg], acc[jf][3][reg]));
      #pragma unroll
      for (int off = 1; off < 16; off <<= 1) m = fmaxf(m, __shfl_xor(m, off, 64));
      if ((lane & 15) == 0) s_rmax[w][jf * 16 + rg + reg] = m;
    }
  }
  // diag c == i: wave i>>6, frag (i>>4)&3, lanes lane&15 == i&15 (rule #20).
  if (w == (i >> 6) && (lane & 15) == (i & 15)) {
    const int cfd = (i >> 4) & 3;
    #pragma unroll
    for (int jf = 0; jf < 4; ++jf) {
      #pragma unroll
      for (int reg = 0; reg < 4; ++reg) {
        float v = acc[jf][0][reg];
        #pragma unroll
        for (int cf = 1; cf < 4; ++cf)
          v = (cfd == cf) ? acc[jf][cf][reg] : v;
        s_diag[jf * 16 + rg + reg] = v;
      }
    }
  }
  __syncthreads();

  #pragma unroll
  for (int jf = 0; jf < 4; ++jf) {
    #pragma unroll
    for (int reg = 0; reg < 4; ++reg) {
      int row = jf * 16 + rg + reg;
      float gm = fmaxf(fmaxf(s_rmax[0][row], s_rmax[1][row]),
                       fmaxf(s_rmax[2][row], s_rmax[3][row]));
      float sE = 0.f;
      #pragma unroll
      for (int cf = 0; cf < 4; ++cf) sE += __expf(acc[jf][cf][reg] - gm);
      #pragma unroll
      for (int off = 1; off < 16; off <<= 1) sE += __shfl_xor(sE, off, 64);
      if ((lane & 15) == 0) s_rsum[w][row] = sE;
    }
  }
  __syncthreads();

  float contrib = 0.f;
  if (t < 64) {
    const int row = t;
    float gm = fmaxf(fmaxf(s_rmax[0][row], s_rmax[1][row]),
                     fmaxf(s_rmax[2][row], s_rmax[3][row]));
    float tot = s_rsum[0][row] + s_rsum[1][row] + s_rsum[2][row] + s_rsum[3][row];
    float lse = __logf(tot) + gm;
    float lbl = (float)label_mat[i * NB + jt * 64 + row];
    contrib = lbl * (s_diag[row] - lse);
  }
  #pragma unroll
  for (int off = 32; off >= 1; off >>= 1) contrib += __shfl_down(contrib, off, 64);
  if (t == 0) atomicAdd(out, contrib * (-1.0f / 256.0f));
}

extern "C" void kernel_launch(void* const* d_in, const int* in_sizes, int n_in,
                              void* d_out, int out_size, void* d_ws, size_t ws_size,
                              hipStream_t stream) {
  const float* x   = (const float*)d_in[0];
  const float* tgt = (const float*)d_in[1];
  const int* mask  = (const int*)d_in[2];
  // d_in[3] = query_labels (unused by the reference computation)
  const int* label_mat = (const int*)d_in[4];
  float* out = (float*)d_out;

  unsigned int* xsT = (unsigned int*)d_ws;                       // 32 MiB bf16 [i][b][l]
  unsigned int* tsT = xsT + (size_t)NB * NB * NL / 2;            // 32 MiB bf16 [i][b][l]
  float* sumx = (float*)(tsT + (size_t)NB * NB * NL / 2);        // 256 KiB f32 [b][i]
  float* sumt = sumx + (size_t)NB * NB;                          // 256 KiB f32 [b][i]

  hipMemsetAsync(out, 0, sizeof(float), stream);
  exp_t<<<dim3(NB, 2), 1024, 0, stream>>>(x, tgt, xsT, tsT, sumx, sumt);
  gemm_lse<<<dim3(1024), 256, 0, stream>>>((const unsigned short*)xsT,
                                           (const unsigned short*)tsT,
                                           sumx, sumt, mask, label_mat, out);
}